// Round 16
// baseline (579.373 us; speedup 1.0000x reference)
//
#include <hip/hip_runtime.h>
#include <hip/hip_bf16.h>

typedef __attribute__((ext_vector_type(8))) short short8;
typedef __attribute__((ext_vector_type(4))) float floatx4;

#define S_LEN  50
#define BATCH  128
#define DIM    512
#define HID    512
#define G3     1536
#define VOCAB  30000
#define TOKENS 6400
#define NB256  118      // ceil(30000/256) vocab chunks in decode
#define NVC    472      // partial columns = NB256 * 4 waves
#define NWG    (25 * NB256)   // 2950 decode blocks

#define N8_WIH   (G3 * DIM / 8)              // 98304
#define N8_WHH   (G3 * HID / 8)              // 98304
#define N8_WOUT  (VOCAB * DIM / 8)           // 1920000
#define N8_GATH  (TOKENS * DIM / 8)          // 409600
#define N8_TOTAL (N8_WIH + N8_WHH + N8_WOUT + N8_GATH)   // 2526208 = 256*9868

__device__ __forceinline__ float bf2f(short u) {
    union { unsigned int i; float f; } c;
    c.i = ((unsigned int)(unsigned short)u) << 16;
    return c.f;
}
__device__ __forceinline__ unsigned short f2bf(float x) {
    __hip_bfloat16 h = __float2bfloat16(x);
    unsigned short u;
    __builtin_memcpy(&u, &h, 2);
    return u;
}
__device__ __forceinline__ void gl_lds16(const void* g, void* l) {
    __builtin_amdgcn_global_load_lds(
        (const __attribute__((address_space(1))) void*)g,
        (__attribute__((address_space(3))) void*)l, 16, 0, 0);
}

// ---------------- fused prep: 3x f32->bf16 convert + embedding gather ----------------
__global__ void k_prep(const float* __restrict__ Wih, const float* __restrict__ Whh,
                       const float* __restrict__ Wout, const float* __restrict__ emb,
                       const int* __restrict__ idx,
                       unsigned short* __restrict__ WihB, unsigned short* __restrict__ WhhB,
                       unsigned short* __restrict__ WoutB, unsigned short* __restrict__ X) {
    int g = blockIdx.x * 256 + threadIdx.x;
    const float* src;
    unsigned short* dst;
    if (g < N8_WIH) {
        src = Wih + (size_t)g * 8;  dst = WihB + (size_t)g * 8;
    } else if (g < N8_WIH + N8_WHH) {
        int h = g - N8_WIH;
        src = Whh + (size_t)h * 8;  dst = WhhB + (size_t)h * 8;
    } else if (g < N8_WIH + N8_WHH + N8_WOUT) {
        int h = g - (N8_WIH + N8_WHH);
        src = Wout + (size_t)h * 8; dst = WoutB + (size_t)h * 8;
    } else {
        int h = g - (N8_WIH + N8_WHH + N8_WOUT);
        int token = h >> 6;
        int chunk = (h & 63) << 3;
        src = emb + (size_t)idx[token] * DIM + chunk;
        dst = X + (size_t)token * DIM + chunk;
    }
    union { short8 v; unsigned short u[8]; } o;
#pragma unroll
    for (int i = 0; i < 8; ++i) o.u[i] = f2bf(src[i]);
    *(short8*)dst = o.v;
}

// ---------------- GI = X @ W_ih^T + b_ih   [6400 x 1536] fp32 ----------------
// 128x128 tile, 4 waves (2x2, per-wave 64x64), BK=64, XOR-swizzled LDS (32 KB).
__launch_bounds__(256)
__global__ void k_gemm_gi(const unsigned short* __restrict__ X,
                          const unsigned short* __restrict__ Wih,
                          const float* __restrict__ b_ih,
                          float* __restrict__ GI) {
    __shared__ unsigned short As[128 * 64];
    __shared__ unsigned short Bs[128 * 64];
    // XCD chunking: 600 blocks = 8 x 75 (bijective); mb-major inside chunk
    int bid = blockIdx.x;
    int wgid = (bid % 8) * 75 + bid / 8;
    int mb = wgid % 50, nb = wgid / 50;
    int m0 = mb * 128, n0 = nb * 128;

    int t = threadIdx.x, w = t >> 6, lane = t & 63;
    int wr = w >> 1, wc = w & 1;

    floatx4 zero = {0.f, 0.f, 0.f, 0.f};
    floatx4 acc[4][4];
#pragma unroll
    for (int mi = 0; mi < 4; ++mi)
#pragma unroll
        for (int ni = 0; ni < 4; ++ni) acc[mi][ni] = zero;

    // staging: thread t owns row t>>1 (0..127), 64B half-row (t&1)
    int srow = t >> 1;
    int scq  = (t & 1) * 32;                // element offset within 64-elem row
    const unsigned short* gA = X   + (size_t)(m0 + srow) * DIM + scq;
    const unsigned short* gB = Wih + (size_t)(n0 + srow) * DIM + scq;
    int wo[4];
#pragma unroll
    for (int q = 0; q < 4; ++q)
        wo[q] = (srow * 128 + scq * 2 + q * 16) ^ ((srow & 7) << 4);

    for (int k0 = 0; k0 < DIM; k0 += 64) {
#pragma unroll
        for (int q = 0; q < 4; ++q) {
            *(short8*)((char*)As + wo[q]) = *(const short8*)(gA + k0 + q * 8);
            *(short8*)((char*)Bs + wo[q]) = *(const short8*)(gB + k0 + q * 8);
        }
        __syncthreads();
#pragma unroll
        for (int kt = 0; kt < 2; ++kt) {
            short8 af[4], bf[4];
#pragma unroll
            for (int mi = 0; mi < 4; ++mi) {
                int row = wr * 64 + mi * 16 + (lane & 15);
                int off = (row * 128 + kt * 64 + (lane >> 4) * 16) ^ ((row & 7) << 4);
                af[mi] = *(const short8*)((const char*)As + off);
            }
#pragma unroll
            for (int ni = 0; ni < 4; ++ni) {
                int row = wc * 64 + ni * 16 + (lane & 15);
                int off = (row * 128 + kt * 64 + (lane >> 4) * 16) ^ ((row & 7) << 4);
                bf[ni] = *(const short8*)((const char*)Bs + off);
            }
#pragma unroll
            for (int mi = 0; mi < 4; ++mi)
#pragma unroll
                for (int ni = 0; ni < 4; ++ni)
                    acc[mi][ni] = __builtin_amdgcn_mfma_f32_16x16x32_bf16(af[mi], bf[ni], acc[mi][ni], 0, 0, 0);
        }
        __syncthreads();
    }
#pragma unroll
    for (int mi = 0; mi < 4; ++mi)
#pragma unroll
        for (int ni = 0; ni < 4; ++ni) {
            int col = n0 + wc * 64 + ni * 16 + (lane & 15);
            float bo = b_ih[col];
#pragma unroll
            for (int r = 0; r < 4; ++r) {
                int row = m0 + wr * 64 + mi * 16 + (lane >> 4) * 4 + r;
                GI[(size_t)row * G3 + col] = acc[mi][ni][r] + bo;
            }
        }
}

// ---------------- GRU single step: 256 blocks x 64 thr (all CUs) ----------------
__launch_bounds__(64)
__global__ void k_gru_step(const float* __restrict__ GI,
                           const unsigned short* __restrict__ Whh,
                           const float* __restrict__ b_hh,
                           float* __restrict__ hf,
                           const unsigned short* __restrict__ hin,
                           unsigned short* __restrict__ hout,
                           int s) {
    int lane = threadIdx.x & 63;
    int bg = blockIdx.x & 7;      // batch group (8 groups of 16)
    int hs = blockIdx.x >> 3;     // hidden slice (32 slices of 16)
    int jc = hs * 16 + (lane & 15);   // hidden unit (N index)

    floatx4 acc0 = {0.f, 0.f, 0.f, 0.f};
    floatx4 acc1 = {0.f, 0.f, 0.f, 0.f};
    floatx4 acc2 = {0.f, 0.f, 0.f, 0.f};
    if (s != 0) {   // at s==0, h0 == 0 -> gh == 0
        const unsigned short* pa  = hin + (size_t)(bg * 16 + (lane & 15)) * HID + (lane >> 4) * 8;
        const unsigned short* pb0 = Whh + (size_t)(0 * HID + jc) * DIM + (lane >> 4) * 8;
        const unsigned short* pb1 = Whh + (size_t)(1 * HID + jc) * DIM + (lane >> 4) * 8;
        const unsigned short* pb2 = Whh + (size_t)(2 * HID + jc) * DIM + (lane >> 4) * 8;
#pragma unroll
        for (int kt = 0; kt < 16; ++kt) {
            short8 a = *(const short8*)(pa + kt * 32);
            acc0 = __builtin_amdgcn_mfma_f32_16x16x32_bf16(a, *(const short8*)(pb0 + kt * 32), acc0, 0, 0, 0);
            acc1 = __builtin_amdgcn_mfma_f32_16x16x32_bf16(a, *(const short8*)(pb1 + kt * 32), acc1, 0, 0, 0);
            acc2 = __builtin_amdgcn_mfma_f32_16x16x32_bf16(a, *(const short8*)(pb2 + kt * 32), acc2, 0, 0, 0);
        }
    }
    float bhr = b_hh[jc], bhz = b_hh[jc + 512], bhn = b_hh[jc + 1024];
#pragma unroll
    for (int r = 0; r < 4; ++r) {
        int brow = bg * 16 + (lane >> 4) * 4 + r;   // batch row (M index)
        int tok = s * BATCH + brow;
        const float* gi = GI + (size_t)tok * G3;
        float rg = 1.f / (1.f + __expf(-(gi[jc] + acc0[r] + bhr)));
        float zg = 1.f / (1.f + __expf(-(gi[jc + 512] + acc1[r] + bhz)));
        float ng = tanhf(gi[jc + 1024] + rg * (acc2[r] + bhn));
        size_t hidx = (size_t)brow * HID + jc;
        float hn = (1.f - zg) * ng + zg * hf[hidx];
        hf[hidx] = hn;
        hout[hidx] = f2bf(hn);
    }
}

// ---------------- decode: 256x256 tile, 8 waves (2Mx4N, 128x64/wave), counted-vmcnt ----------------
// 512 thr. K-tiles of 64, dbuf. Per iter: issue 8 global_load_lds for tile kt+1
// (linear LDS dest, swizzle-inverse global src), wait vmcnt(8), s_barrier,
// MFMA (64/wave) with setprio, s_barrier. LDS traffic/K-tile: 192 KB (vs 256 at 4x4).
__launch_bounds__(512)
__global__ void k_decode(const unsigned short* __restrict__ HS,
                         const unsigned short* __restrict__ Wout,
                         const float* __restrict__ b_out,
                         float* __restrict__ partial) {
    __shared__ unsigned short As[2][256 * 64];
    __shared__ unsigned short Bs[2][256 * 64];

    // bijective XCD chunk swizzle (nwg=2950, q=368, r=6)
    int bid = blockIdx.x;
    int xcd = bid & 7, pos = bid >> 3;
    int p = (xcd < 6 ? xcd * 369 : 2214 + (xcd - 6) * 368) + pos;
    // supergroup order: 14 groups of 8 nb + 1 group of 6 nb; mb-major within group
    int sgrp = p / 200;             // 25 mb * 8 nb = 200 blocks per full group
    int rr   = p - sgrp * 200;
    int mb, nb;
    if (sgrp < 14) { mb = rr >> 3; nb = sgrp * 8 + (rr & 7); }
    else           { int q6 = rr / 6; mb = q6; nb = 112 + (rr - q6 * 6); }
    int m0 = mb * 256, n0 = nb * 256;

    int t = threadIdx.x, w = t >> 6, lane = t & 63;
    int wr = w >> 2, wc = w & 3;            // 2x4 wave grid; per-wave 128(M)x64(N)

    floatx4 zero = {0.f, 0.f, 0.f, 0.f};
    floatx4 acc[8][4];
#pragma unroll
    for (int mi = 0; mi < 8; ++mi)
#pragma unroll
        for (int ni = 0; ni < 4; ++ni) acc[mi][ni] = zero;

    // ---- staging: each wave stages four 8-row chunks (1 KB each) of A and of B.
    // LDS dest linear (chunk*1024 + lane*16); swizzle via pre-swizzled global src:
    // content at LDS byte d = global(row, (d&127) ^ ((row&7)<<4)); row&7 == lane>>3.
    int r8  = lane >> 3;                        // 0..7
    int cbs = ((lane & 7) ^ r8) * 16;           // swizzle-inverse source byte offset
    const char* gAq[4];
    const char* gBq[4];
#pragma unroll
    for (int q = 0; q < 4; ++q) {
        int chunk = w * 4 + q;                  // 0..31
        int row = chunk * 8 + r8;               // tile row 0..255
        gAq[q] = (const char*)(HS + (size_t)(m0 + row) * DIM) + cbs;
        int v = n0 + row; if (v > VOCAB - 1) v = VOCAB - 1;
        gBq[q] = (const char*)(Wout + (size_t)v * DIM) + cbs;
    }
    int ldsoff[4];
#pragma unroll
    for (int q = 0; q < 4; ++q) ldsoff[q] = (w * 4 + q) * 1024;

    // swizzled read offsets (bytes) per wave fragment
    int roA[8][2], roB[4][2];
#pragma unroll
    for (int mi = 0; mi < 8; ++mi)
#pragma unroll
        for (int kh = 0; kh < 2; ++kh) {
            int row = wr * 128 + mi * 16 + (lane & 15);
            roA[mi][kh] = (row * 128 + kh * 64 + (lane >> 4) * 16) ^ ((row & 7) << 4);
        }
#pragma unroll
    for (int ni = 0; ni < 4; ++ni)
#pragma unroll
        for (int kh = 0; kh < 2; ++kh) {
            int row = wc * 64 + ni * 16 + (lane & 15);
            roB[ni][kh] = (row * 128 + kh * 64 + (lane >> 4) * 16) ^ ((row & 7) << 4);
        }

#define STAGE(kt, buf) do { int ko_ = (kt) * 128;                          \
        gl_lds16(gAq[0] + ko_, (char*)As[buf] + ldsoff[0]);                \
        gl_lds16(gAq[1] + ko_, (char*)As[buf] + ldsoff[1]);                \
        gl_lds16(gAq[2] + ko_, (char*)As[buf] + ldsoff[2]);                \
        gl_lds16(gAq[3] + ko_, (char*)As[buf] + ldsoff[3]);                \
        gl_lds16(gBq[0] + ko_, (char*)Bs[buf] + ldsoff[0]);                \
        gl_lds16(gBq[1] + ko_, (char*)Bs[buf] + ldsoff[1]);                \
        gl_lds16(gBq[2] + ko_, (char*)Bs[buf] + ldsoff[2]);                \
        gl_lds16(gBq[3] + ko_, (char*)Bs[buf] + ldsoff[3]); } while (0)

    STAGE(0, 0);
    __builtin_amdgcn_sched_barrier(0);

    for (int kt = 0; kt < 8; ++kt) {
        int cur = kt & 1;
        if (kt < 7) {
            STAGE(kt + 1, cur ^ 1);
            __builtin_amdgcn_sched_barrier(0);
            asm volatile("s_waitcnt vmcnt(8)" ::: "memory");   // tile kt landed; kt+1 in flight
        } else {
            asm volatile("s_waitcnt vmcnt(0)" ::: "memory");
        }
        __builtin_amdgcn_sched_barrier(0);
        __builtin_amdgcn_s_barrier();                          // all waves' tile-kt loads landed
        __builtin_amdgcn_sched_barrier(0);
        __builtin_amdgcn_s_setprio(1);
#pragma unroll
        for (int kh = 0; kh < 2; ++kh) {
            short8 af[8], bf[4];
#pragma unroll
            for (int mi = 0; mi < 8; ++mi)
                af[mi] = *(const short8*)((const char*)As[cur] + roA[mi][kh]);
#pragma unroll
            for (int ni = 0; ni < 4; ++ni)
                bf[ni] = *(const short8*)((const char*)Bs[cur] + roB[ni][kh]);
#pragma unroll
            for (int mi = 0; mi < 8; ++mi)
#pragma unroll
                for (int ni = 0; ni < 4; ++ni)
                    acc[mi][ni] = __builtin_amdgcn_mfma_f32_16x16x32_bf16(af[mi], bf[ni], acc[mi][ni], 0, 0, 0);
        }
        __builtin_amdgcn_s_setprio(0);
        __builtin_amdgcn_sched_barrier(0);
        __builtin_amdgcn_s_barrier();                          // buf[cur] free for overwrite
        __builtin_amdgcn_sched_barrier(0);
    }
#undef STAGE

    // epilogue: exp + per-token partial sums over this wave's 64 vocab cols
    float esum[8][4];   // [mi][r]
#pragma unroll
    for (int mi = 0; mi < 8; ++mi)
#pragma unroll
        for (int r = 0; r < 4; ++r) esum[mi][r] = 0.f;
#pragma unroll
    for (int ni = 0; ni < 4; ++ni) {
        int v = n0 + wc * 64 + ni * 16 + (lane & 15);
        bool ok = v < VOCAB;
        float bo = ok ? b_out[v] : 0.f;
#pragma unroll
        for (int mi = 0; mi < 8; ++mi)
#pragma unroll
            for (int r = 0; r < 4; ++r) {
                float logit = acc[mi][ni][r] + bo;
                esum[mi][r] += ok ? __expf(logit) : 0.f;
            }
    }
#pragma unroll
    for (int d = 1; d < 16; d <<= 1)
#pragma unroll
        for (int mi = 0; mi < 8; ++mi)
#pragma unroll
            for (int r = 0; r < 4; ++r) esum[mi][r] += __shfl_xor(esum[mi][r], d, 64);
    if ((lane & 15) == 0) {
#pragma unroll
        for (int mi = 0; mi < 8; ++mi)
#pragma unroll
            for (int r = 0; r < 4; ++r) {
                int tok = m0 + wr * 128 + mi * 16 + (lane >> 4) * 4 + r;
                partial[(size_t)tok * 512 + nb * 4 + wc] = esum[mi][r];
            }
    }
}

// ---------------- fused: target logit + lse reduce (one wave per token) ----------------
__global__ void k_lse_tlg(const float* __restrict__ partial,
                          const unsigned short* __restrict__ HS,
                          const unsigned short* __restrict__ Wout,
                          const float* __restrict__ b_out,
                          const int* __restrict__ target,
                          float* __restrict__ lse, float* __restrict__ tlg) {
    int tok = blockIdx.x * 4 + (threadIdx.x >> 6);
    int lane = threadIdx.x & 63;
    int tg = target[tok];
    short8 a = *(const short8*)(HS + (size_t)tok * DIM + lane * 8);
    short8 b = *(const short8*)(Wout + (size_t)tg * DIM + lane * 8);
    float s = 0.f;
#pragma unroll
    for (int i = 0; i < 8; ++i) s += bf2f(a[i]) * bf2f(b[i]);
    float s2 = 0.f;
    for (int j = lane; j < NVC; j += 64) s2 += partial[(size_t)tok * 512 + j];
#pragma unroll
    for (int d = 1; d < 64; d <<= 1) {
        s  += __shfl_xor(s, d, 64);
        s2 += __shfl_xor(s2, d, 64);
    }
    if (lane == 0) {
        tlg[tok] = s + b_out[tg];
        lse[tok] = logf(s2);
    }
}

// ---------------- loss + masked mean ----------------
__global__ void k_finalize(const float* __restrict__ lse, const float* __restrict__ tlg,
                           const int* __restrict__ target, float* __restrict__ out) {
    __shared__ float ssum[256];
    __shared__ float scnt[256];
    int t = threadIdx.x;
    float ls = 0.f, lc = 0.f;
    for (int i = t; i < TOKENS; i += 256) {
        int tg = target[i];
        float loss = (tg != 0) ? (lse[i] - tlg[i]) : 0.f;
        out[i] = loss;
        ls += loss;
        lc += (tg != 0) ? 1.f : 0.f;
    }
    ssum[t] = ls; scnt[t] = lc;
    __syncthreads();
    for (int d = 128; d > 0; d >>= 1) {
        if (t < d) { ssum[t] += ssum[t + d]; scnt[t] += scnt[t + d]; }
        __syncthreads();
    }
    if (t == 0) out[TOKENS] = ssum[0] / fmaxf(scnt[0], 1.f);
}

extern "C" void kernel_launch(void* const* d_in, const int* in_sizes, int n_in,
                              void* d_out, int out_size, void* d_ws, size_t ws_size,
                              hipStream_t stream) {
    const int*   review_input  = (const int*)d_in[2];
    const int*   review_target = (const int*)d_in[3];
    const float* word_emb      = (const float*)d_in[4];
    const float* W_ih          = (const float*)d_in[5];
    const float* W_hh          = (const float*)d_in[6];
    const float* b_ih          = (const float*)d_in[7];
    const float* b_hh          = (const float*)d_in[8];
    const float* W_out         = (const float*)d_in[9];
    const float* b_out         = (const float*)d_in[10];
    float* out = (float*)d_out;

    char* ws = (char*)d_ws;
    size_t off = 0;
    auto alloc = [&](size_t n) { char* p = ws + off; off += (n + 255) & ~(size_t)255; return p; };
    unsigned short* Xb    = (unsigned short*)alloc((size_t)TOKENS * DIM * 2);
    unsigned short* Wihb  = (unsigned short*)alloc((size_t)G3 * DIM * 2);
    unsigned short* Whhb  = (unsigned short*)alloc((size_t)G3 * HID * 2);
    unsigned short* Woutb = (unsigned short*)alloc((size_t)VOCAB * DIM * 2);
    unsigned short* HS    = (unsigned short*)alloc((size_t)TOKENS * HID * 2);
    float* hf      = (float*)alloc((size_t)BATCH * HID * 4);
    float* GI      = (float*)alloc((size_t)TOKENS * G3 * 4);
    float* partial = (float*)alloc((size_t)TOKENS * 512 * 4);
    float* lse     = (float*)alloc((size_t)TOKENS * 4);
    float* tlg     = (float*)alloc((size_t)TOKENS * 4);
    (void)ws_size; (void)in_sizes; (void)n_in; (void)out_size;

    // fused weight conversions + embedding gather (exact-cover grid)
    k_prep<<<dim3(N8_TOTAL / 256), dim3(256), 0, stream>>>(
        W_ih, W_hh, W_out, word_emb, review_input, Wihb, Whhb, Woutb, Xb);

    // GI = X @ W_ih^T + b_ih (128x128 swizzled tile)
    k_gemm_gi<<<dim3(600), dim3(256), 0, stream>>>(Xb, Wihb, b_ih, GI);

    // GRU recurrence: 50 per-step kernels, 256 blocks x 64 thr (all CUs)
    hipMemsetAsync(hf, 0, (size_t)BATCH * HID * 4, stream);
    for (int s = 0; s < S_LEN; ++s) {
        const unsigned short* hin = s ? (HS + (size_t)(s - 1) * BATCH * HID) : HS;
        unsigned short* hout = HS + (size_t)s * BATCH * HID;
        k_gru_step<<<dim3(256), dim3(64), 0, stream>>>(GI, Whhb, b_hh, hf, hin, hout, s);
    }

    // decode: partial exp-sums, fused lse+tlogit, final loss
    k_decode<<<dim3(NWG), dim3(512), 0, stream>>>(HS, Woutb, b_out, partial);
    k_lse_tlg<<<dim3(TOKENS / 4), dim3(256), 0, stream>>>(partial, HS, Woutb, b_out, review_target, lse, tlg);
    k_finalize<<<dim3(1), dim3(256), 0, stream>>>(lse, tlg, review_target, out);
}

// Round 17
// 520.669 us; speedup vs baseline: 1.1127x; 1.1127x over previous
//
#include <hip/hip_runtime.h>
#include <hip/hip_bf16.h>

typedef __attribute__((ext_vector_type(8))) short short8;
typedef __attribute__((ext_vector_type(4))) float floatx4;

#define S_LEN  50
#define BATCH  128
#define DIM    512
#define HID    512
#define G3     1536
#define VOCAB  30000
#define TOKENS 6400
#define NB256  118      // ceil(30000/256) vocab chunks in decode
#define NVC    472      // partial columns = NB256 * 4 waves
#define NWG    (25 * NB256)   // 2950 decode blocks

__device__ __forceinline__ float bf2f(short u) {
    union { unsigned int i; float f; } c;
    c.i = ((unsigned int)(unsigned short)u) << 16;
    return c.f;
}
__device__ __forceinline__ unsigned short f2bf(float x) {
    __hip_bfloat16 h = __float2bfloat16(x);
    unsigned short u;
    __builtin_memcpy(&u, &h, 2);
    return u;
}
__device__ __forceinline__ void gl_lds16(const void* g, void* l) {
    __builtin_amdgcn_global_load_lds(
        (const __attribute__((address_space(1))) void*)g,
        (__attribute__((address_space(3))) void*)l, 16, 0, 0);
}

// ---------------- f32 -> bf16 bulk convert (8 elems/thread) ----------------
__global__ void k_cvt_bf16(const float* __restrict__ src,
                           unsigned short* __restrict__ dst, int n8) {
    int g = blockIdx.x * 256 + threadIdx.x;
    if (g >= n8) return;
    const float* s = src + (size_t)g * 8;
    union { short8 v; unsigned short u[8]; } o;
#pragma unroll
    for (int i = 0; i < 8; ++i) o.u[i] = f2bf(s[i]);
    *(short8*)(dst + (size_t)g * 8) = o.v;
}

// ---------------- embedding gather + convert: X[token][512] bf16 ----------------
__global__ void k_gather_x(const float* __restrict__ emb, const int* __restrict__ idx,
                           unsigned short* __restrict__ X) {
    int g = blockIdx.x * 256 + threadIdx.x;   // 8-elem group; total TOKENS*DIM/8
    int token = g >> 6;                       // 64 groups per token
    int chunk = (g & 63) << 3;
    const float* src = emb + (size_t)idx[token] * DIM + chunk;
    union { short8 v; unsigned short u[8]; } o;
#pragma unroll
    for (int i = 0; i < 8; ++i) o.u[i] = f2bf(src[i]);
    *(short8*)(X + (size_t)token * DIM + chunk) = o.v;
}

// ---------------- GI = X @ W_ih^T + b_ih   [6400 x 1536] fp32 ----------------
__launch_bounds__(256)
__global__ void k_gemm_gi(const unsigned short* __restrict__ X,
                          const unsigned short* __restrict__ Wih,
                          const float* __restrict__ b_ih,
                          float* __restrict__ GI) {
    __shared__ unsigned short As[64][72];
    __shared__ unsigned short Bs[64][72];
    int m0 = blockIdx.x * 64;
    int n0 = blockIdx.y * 64;
    int t = threadIdx.x;
    int w = t >> 6, lane = t & 63;
    floatx4 zero = {0.f, 0.f, 0.f, 0.f};
    floatx4 acc[4];
#pragma unroll
    for (int i = 0; i < 4; ++i) acc[i] = zero;
    int srow = t >> 2, scol = (t & 3) * 16;
    for (int k0 = 0; k0 < DIM; k0 += 64) {
        *(short8*)&As[srow][scol]     = *(const short8*)(X   + (size_t)(m0 + srow) * DIM + k0 + scol);
        *(short8*)&As[srow][scol + 8] = *(const short8*)(X   + (size_t)(m0 + srow) * DIM + k0 + scol + 8);
        *(short8*)&Bs[srow][scol]     = *(const short8*)(Wih + (size_t)(n0 + srow) * DIM + k0 + scol);
        *(short8*)&Bs[srow][scol + 8] = *(const short8*)(Wih + (size_t)(n0 + srow) * DIM + k0 + scol + 8);
        __syncthreads();
#pragma unroll
        for (int kt = 0; kt < 2; ++kt) {
            short8 a = *(const short8*)&As[w * 16 + (lane & 15)][kt * 32 + (lane >> 4) * 8];
#pragma unroll
            for (int nt = 0; nt < 4; ++nt) {
                short8 b = *(const short8*)&Bs[nt * 16 + (lane & 15)][kt * 32 + (lane >> 4) * 8];
                acc[nt] = __builtin_amdgcn_mfma_f32_16x16x32_bf16(a, b, acc[nt], 0, 0, 0);
            }
        }
        __syncthreads();
    }
#pragma unroll
    for (int nt = 0; nt < 4; ++nt)
#pragma unroll
        for (int r = 0; r < 4; ++r) {
            int row = m0 + w * 16 + (lane >> 4) * 4 + r;
            int col = n0 + nt * 16 + (lane & 15);
            GI[(size_t)row * G3 + col] = acc[nt][r] + b_ih[col];
        }
}

// ---------------- GRU single step: 256 blocks x 64 thr (all CUs) ----------------
__launch_bounds__(64)
__global__ void k_gru_step(const float* __restrict__ GI,
                           const unsigned short* __restrict__ Whh,
                           const float* __restrict__ b_hh,
                           float* __restrict__ hf,
                           const unsigned short* __restrict__ hin,
                           unsigned short* __restrict__ hout,
                           int s) {
    int lane = threadIdx.x & 63;
    int bg = blockIdx.x & 7;      // batch group (8 groups of 16)
    int hs = blockIdx.x >> 3;     // hidden slice (32 slices of 16)
    int jc = hs * 16 + (lane & 15);   // hidden unit (N index)

    const unsigned short* pa  = hin + (size_t)(bg * 16 + (lane & 15)) * HID + (lane >> 4) * 8;
    const unsigned short* pb0 = Whh + (size_t)(0 * HID + jc) * DIM + (lane >> 4) * 8;
    const unsigned short* pb1 = Whh + (size_t)(1 * HID + jc) * DIM + (lane >> 4) * 8;
    const unsigned short* pb2 = Whh + (size_t)(2 * HID + jc) * DIM + (lane >> 4) * 8;

    floatx4 acc0 = {0.f, 0.f, 0.f, 0.f};
    floatx4 acc1 = {0.f, 0.f, 0.f, 0.f};
    floatx4 acc2 = {0.f, 0.f, 0.f, 0.f};
#pragma unroll
    for (int kt = 0; kt < 16; ++kt) {
        short8 a = *(const short8*)(pa + kt * 32);
        acc0 = __builtin_amdgcn_mfma_f32_16x16x32_bf16(a, *(const short8*)(pb0 + kt * 32), acc0, 0, 0, 0);
        acc1 = __builtin_amdgcn_mfma_f32_16x16x32_bf16(a, *(const short8*)(pb1 + kt * 32), acc1, 0, 0, 0);
        acc2 = __builtin_amdgcn_mfma_f32_16x16x32_bf16(a, *(const short8*)(pb2 + kt * 32), acc2, 0, 0, 0);
    }
    float bhr = b_hh[jc], bhz = b_hh[jc + 512], bhn = b_hh[jc + 1024];
#pragma unroll
    for (int r = 0; r < 4; ++r) {
        int brow = bg * 16 + (lane >> 4) * 4 + r;   // batch row (M index)
        int tok = s * BATCH + brow;
        const float* gi = GI + (size_t)tok * G3;
        float rg = 1.f / (1.f + __expf(-(gi[jc] + acc0[r] + bhr)));
        float zg = 1.f / (1.f + __expf(-(gi[jc + 512] + acc1[r] + bhz)));
        float ng = tanhf(gi[jc + 1024] + rg * (acc2[r] + bhn));
        size_t hidx = (size_t)brow * HID + jc;
        float hn = (1.f - zg) * ng + zg * hf[hidx];
        hf[hidx] = hn;
        hout[hidx] = f2bf(hn);
    }
}

// ---------------- decode: 256x256 tile, counted-vmcnt global_load_lds pipeline ----------------
// R14-proven: 16 waves (4x4), 64x64 per wave. K-tiles of 64, dbuf. Per iter:
// issue 4 global_load_lds for tile kt+1 (linear LDS dest, swizzle-inverse global
// src), wait vmcnt(4), s_barrier, MFMA on buf[kt&1], s_barrier. No vmcnt(0)
// drain in-loop (T4).
__launch_bounds__(1024, 4)
__global__ void k_decode(const unsigned short* __restrict__ HS,
                         const unsigned short* __restrict__ Wout,
                         const float* __restrict__ b_out,
                         float* __restrict__ partial) {
    __shared__ unsigned short As[2][256 * 64];
    __shared__ unsigned short Bs[2][256 * 64];

    // bijective XCD chunk swizzle (nwg=2950, q=368, r=6)
    int bid = blockIdx.x;
    int xcd = bid & 7, pos = bid >> 3;
    int p = (xcd < 6 ? xcd * 369 : 2214 + (xcd - 6) * 368) + pos;
    // supergroup order: 14 groups of 8 nb + 1 group of 6 nb; mb-major within group
    int sgrp = p / 200;             // 25 mb * 8 nb = 200 blocks per full group
    int rr   = p - sgrp * 200;
    int mb, nb;
    if (sgrp < 14) { mb = rr >> 3; nb = sgrp * 8 + (rr & 7); }
    else           { int q6 = rr / 6; mb = q6; nb = 112 + (rr - q6 * 6); }
    int m0 = mb * 256, n0 = nb * 256;

    int t = threadIdx.x, w = t >> 6, lane = t & 63;
    int wr = w >> 2, wc = w & 3;            // 4x4 wave grid

    floatx4 zero = {0.f, 0.f, 0.f, 0.f};
    floatx4 acc[4][4];
#pragma unroll
    for (int mi = 0; mi < 4; ++mi)
#pragma unroll
        for (int ni = 0; ni < 4; ++ni) acc[mi][ni] = zero;

    // ---- staging setup: each wave stages two 8-row chunks (1 KB each) of A and B.
    // LDS dest is linear (chunk*1024 + lane*16); swizzle achieved by pre-swizzling
    // the per-lane GLOBAL source: content at LDS byte d must be
    // global(row, (d&127) ^ ((row&7)<<4)); within an 8-row chunk row&7 == lane>>3.
    int r8  = lane >> 3;                        // 0..7
    int cbs = ((lane & 7) ^ r8) * 16;           // swizzle-inverse source byte offset
    int c0 = w * 2, c1 = c0 + 1;                // this wave's chunk ids (0..31)
    int rA0 = c0 * 8 + r8, rA1 = c1 * 8 + r8;   // tile rows 0..255
    const char* gA0 = (const char*)(HS + (size_t)(m0 + rA0) * DIM) + cbs;
    const char* gA1 = (const char*)(HS + (size_t)(m0 + rA1) * DIM) + cbs;
    int v0 = n0 + rA0; if (v0 > VOCAB - 1) v0 = VOCAB - 1;
    int v1 = n0 + rA1; if (v1 > VOCAB - 1) v1 = VOCAB - 1;
    const char* gB0 = (const char*)(Wout + (size_t)v0 * DIM) + cbs;
    const char* gB1 = (const char*)(Wout + (size_t)v1 * DIM) + cbs;

    // swizzled read offsets (bytes) per wave fragment — identical to R11
    int roA[4][2], roB[4][2];
#pragma unroll
    for (int mi = 0; mi < 4; ++mi)
#pragma unroll
        for (int kh = 0; kh < 2; ++kh) {
            int row = wr * 64 + mi * 16 + (lane & 15);
            roA[mi][kh] = (row * 128 + kh * 64 + (lane >> 4) * 16) ^ ((row & 7) << 4);
        }
#pragma unroll
    for (int ni = 0; ni < 4; ++ni)
#pragma unroll
        for (int kh = 0; kh < 2; ++kh) {
            int row = wc * 64 + ni * 16 + (lane & 15);
            roB[ni][kh] = (row * 128 + kh * 64 + (lane >> 4) * 16) ^ ((row & 7) << 4);
        }

#define STAGE(kt, buf) do { int ko_ = (kt) * 128;                        \
        gl_lds16(gA0 + ko_, (char*)As[buf] + c0 * 1024);                 \
        gl_lds16(gA1 + ko_, (char*)As[buf] + c1 * 1024);                 \
        gl_lds16(gB0 + ko_, (char*)Bs[buf] + c0 * 1024);                 \
        gl_lds16(gB1 + ko_, (char*)Bs[buf] + c1 * 1024); } while (0)

    STAGE(0, 0);
    __builtin_amdgcn_sched_barrier(0);

    for (int kt = 0; kt < 8; ++kt) {
        int cur = kt & 1;
        if (kt < 7) {
            STAGE(kt + 1, cur ^ 1);
            __builtin_amdgcn_sched_barrier(0);
            asm volatile("s_waitcnt vmcnt(4)" ::: "memory");   // tile kt landed; tile kt+1 in flight
        } else {
            asm volatile("s_waitcnt vmcnt(0)" ::: "memory");
        }
        __builtin_amdgcn_sched_barrier(0);
        __builtin_amdgcn_s_barrier();                          // all waves' tile-kt loads landed
        __builtin_amdgcn_sched_barrier(0);
#pragma unroll
        for (int kh = 0; kh < 2; ++kh) {
            short8 af[4], bf[4];
#pragma unroll
            for (int mi = 0; mi < 4; ++mi)
                af[mi] = *(const short8*)((const char*)As[cur] + roA[mi][kh]);
#pragma unroll
            for (int ni = 0; ni < 4; ++ni)
                bf[ni] = *(const short8*)((const char*)Bs[cur] + roB[ni][kh]);
#pragma unroll
            for (int mi = 0; mi < 4; ++mi)
#pragma unroll
                for (int ni = 0; ni < 4; ++ni)
                    acc[mi][ni] = __builtin_amdgcn_mfma_f32_16x16x32_bf16(af[mi], bf[ni], acc[mi][ni], 0, 0, 0);
        }
        __builtin_amdgcn_sched_barrier(0);
        __builtin_amdgcn_s_barrier();                          // buf[cur] free for overwrite
        __builtin_amdgcn_sched_barrier(0);
    }
#undef STAGE

    // epilogue: exp + per-token partial sums over this wave's 64 vocab cols
    float esum[4][4];   // [mi][r]
#pragma unroll
    for (int mi = 0; mi < 4; ++mi)
#pragma unroll
        for (int r = 0; r < 4; ++r) esum[mi][r] = 0.f;
#pragma unroll
    for (int ni = 0; ni < 4; ++ni) {
        int v = n0 + wc * 64 + ni * 16 + (lane & 15);
        bool ok = v < VOCAB;
        float bo = ok ? b_out[v] : 0.f;
#pragma unroll
        for (int mi = 0; mi < 4; ++mi)
#pragma unroll
            for (int r = 0; r < 4; ++r) {
                float logit = acc[mi][ni][r] + bo;
                esum[mi][r] += ok ? __expf(logit) : 0.f;
            }
    }
#pragma unroll
    for (int d = 1; d < 16; d <<= 1)
#pragma unroll
        for (int mi = 0; mi < 4; ++mi)
#pragma unroll
            for (int r = 0; r < 4; ++r) esum[mi][r] += __shfl_xor(esum[mi][r], d, 64);
    if ((lane & 15) == 0) {
#pragma unroll
        for (int mi = 0; mi < 4; ++mi)
#pragma unroll
            for (int r = 0; r < 4; ++r) {
                int tok = m0 + wr * 64 + mi * 16 + (lane >> 4) * 4 + r;
                partial[(size_t)tok * 512 + nb * 4 + wc] = esum[mi][r];
            }
    }
}

// ---------------- fixed-order reduce of partials -> lse ----------------
__global__ void k_reduce_lse(const float* __restrict__ partial, float* __restrict__ lse) {
    int tok = blockIdx.x * 4 + (threadIdx.x >> 6);
    int lane = threadIdx.x & 63;
    float s = 0.f;
    for (int j = lane; j < NVC; j += 64) s += partial[(size_t)tok * 512 + j];
#pragma unroll
    for (int d = 1; d < 64; d <<= 1) s += __shfl_xor(s, d, 64);
    if (lane == 0) lse[tok] = logf(s);
}

// ---------------- target logit: one wave per token ----------------
__global__ void k_tlogit(const unsigned short* __restrict__ HS,
                         const unsigned short* __restrict__ Wout,
                         const float* __restrict__ b_out,
                         const int* __restrict__ target,
                         float* __restrict__ tlg) {
    int tok = blockIdx.x * 4 + (threadIdx.x >> 6);
    int lane = threadIdx.x & 63;
    int tg = target[tok];
    short8 a = *(const short8*)(HS + (size_t)tok * DIM + lane * 8);
    short8 b = *(const short8*)(Wout + (size_t)tg * DIM + lane * 8);
    float s = 0.f;
#pragma unroll
    for (int i = 0; i < 8; ++i) s += bf2f(a[i]) * bf2f(b[i]);
#pragma unroll
    for (int d = 1; d < 64; d <<= 1) s += __shfl_xor(s, d, 64);
    if (lane == 0) tlg[tok] = s + b_out[tg];
}

// ---------------- loss + masked mean ----------------
__global__ void k_finalize(const float* __restrict__ lse, const float* __restrict__ tlg,
                           const int* __restrict__ target, float* __restrict__ out) {
    __shared__ float ssum[256];
    __shared__ float scnt[256];
    int t = threadIdx.x;
    float ls = 0.f, lc = 0.f;
    for (int i = t; i < TOKENS; i += 256) {
        int tg = target[i];
        float loss = (tg != 0) ? (lse[i] - tlg[i]) : 0.f;
        out[i] = loss;
        ls += loss;
        lc += (tg != 0) ? 1.f : 0.f;
    }
    ssum[t] = ls; scnt[t] = lc;
    __syncthreads();
    for (int d = 128; d > 0; d >>= 1) {
        if (t < d) { ssum[t] += ssum[t + d]; scnt[t] += scnt[t + d]; }
        __syncthreads();
    }
    if (t == 0) out[TOKENS] = ssum[0] / fmaxf(scnt[0], 1.f);
}

extern "C" void kernel_launch(void* const* d_in, const int* in_sizes, int n_in,
                              void* d_out, int out_size, void* d_ws, size_t ws_size,
                              hipStream_t stream) {
    const int*   review_input  = (const int*)d_in[2];
    const int*   review_target = (const int*)d_in[3];
    const float* word_emb      = (const float*)d_in[4];
    const float* W_ih          = (const float*)d_in[5];
    const float* W_hh          = (const float*)d_in[6];
    const float* b_ih          = (const float*)d_in[7];
    const float* b_hh          = (const float*)d_in[8];
    const float* W_out         = (const float*)d_in[9];
    const float* b_out         = (const float*)d_in[10];
    float* out = (float*)d_out;

    char* ws = (char*)d_ws;
    size_t off = 0;
    auto alloc = [&](size_t n) { char* p = ws + off; off += (n + 255) & ~(size_t)255; return p; };
    unsigned short* Xb    = (unsigned short*)alloc((size_t)TOKENS * DIM * 2);
    unsigned short* Wihb  = (unsigned short*)alloc((size_t)G3 * DIM * 2);
    unsigned short* Whhb  = (unsigned short*)alloc((size_t)G3 * HID * 2);
    unsigned short* Woutb = (unsigned short*)alloc((size_t)VOCAB * DIM * 2);
    unsigned short* HS    = (unsigned short*)alloc((size_t)TOKENS * HID * 2);
    unsigned short* hzero = (unsigned short*)alloc((size_t)BATCH * HID * 2);
    float* hf      = (float*)alloc((size_t)BATCH * HID * 4);
    float* GI      = (float*)alloc((size_t)TOKENS * G3 * 4);
    float* partial = (float*)alloc((size_t)TOKENS * 512 * 4);
    float* lse     = (float*)alloc((size_t)TOKENS * 4);
    float* tlg     = (float*)alloc((size_t)TOKENS * 4);
    (void)ws_size; (void)in_sizes; (void)n_in; (void)out_size;

    // weight conversions + embedding gather
    k_cvt_bf16<<<dim3((G3 * DIM / 8 + 255) / 256), dim3(256), 0, stream>>>(W_ih, Wihb, G3 * DIM / 8);
    k_cvt_bf16<<<dim3((G3 * HID / 8 + 255) / 256), dim3(256), 0, stream>>>(W_hh, Whhb, G3 * HID / 8);
    k_cvt_bf16<<<dim3((VOCAB * DIM / 8 + 255) / 256), dim3(256), 0, stream>>>(W_out, Woutb, VOCAB * DIM / 8);
    k_gather_x<<<dim3(TOKENS * DIM / 8 / 256), dim3(256), 0, stream>>>(word_emb, review_input, Xb);

    // GI = X @ W_ih^T + b_ih
    k_gemm_gi<<<dim3(TOKENS / 64, G3 / 64), dim3(256), 0, stream>>>(Xb, Wihb, b_ih, GI);

    // GRU recurrence: 50 per-step kernels, 256 blocks x 64 thr (all CUs)
    hipMemsetAsync(hf, 0, (size_t)BATCH * HID * 4, stream);
    hipMemsetAsync(hzero, 0, (size_t)BATCH * HID * 2, stream);
    for (int s = 0; s < S_LEN; ++s) {
        const unsigned short* hin = s ? (HS + (size_t)(s - 1) * BATCH * HID) : hzero;
        unsigned short* hout = HS + (size_t)s * BATCH * HID;
        k_gru_step<<<dim3(256), dim3(64), 0, stream>>>(GI, Whhb, b_hh, hf, hin, hout, s);
    }

    // decode: partial exp-sums, reduce to lse, target logits, final loss
    k_decode<<<dim3(NWG), dim3(1024), 0, stream>>>(HS, Woutb, b_out, partial);
    k_reduce_lse<<<dim3(TOKENS / 4), dim3(256), 0, stream>>>(partial, lse);
    k_tlogit<<<dim3(TOKENS / 4), dim3(256), 0, stream>>>(HS, Woutb, b_out, review_target, tlg);
    k_finalize<<<dim3(1), dim3(256), 0, stream>>>(lse, tlg, review_target, out);
}